// Round 12
// baseline (539.257 us; speedup 1.0000x reference)
//
#include <hip/hip_runtime.h>
#include <math.h>

#define SL 2048   // sequence length L
#define NB 32     // batch
#define NH 128    // feature dim H
#define NP 256    // state dim P (complex)
#define NP2 512   // interleaved real/imag columns

typedef short bf16x8 __attribute__((ext_vector_type(8)));
typedef float f32x4  __attribute__((ext_vector_type(4)));

static __device__ __forceinline__ unsigned short f2bf(float x) {
    unsigned u = __float_as_uint(x);
    return (unsigned short)((u + 0x7fffu + ((u >> 16) & 1u)) >> 16);  // RNE
}
static __device__ __forceinline__ float bf2f(unsigned short h) {
    return __uint_as_float(((unsigned)h) << 16);
}
static __device__ __forceinline__ void discretize(
    const float* __restrict__ logLr, const float* __restrict__ Lim,
    const float* __restrict__ logDt, int p, float& wr, float& wi)
{
    const float Lr = expf(logLr[p]);
    const float dt = expf(logDt[p]);
    const float ew = expf(-Lr * dt);
    const float ang = Lim[p] * dt;
    wr = ew * cosf(ang); wi = ew * sinf(ang);
}

// Software grid barrier: plain launch, all 1024 blocks co-resident
// (capacity = 256 CU x 4 blocks/CU at (256,4); LDS 25216 -> 6/CU).
// Device-scope atomics are cross-XCD coherent (m20); __threadfence()
// release/acquire makes the non-atomic part[] traffic visible.
static __device__ __forceinline__ void gbar(unsigned* __restrict__ ctr,
                                            unsigned target) {
    __threadfence();                 // release: prior global writes visible
    __syncthreads();
    if (threadIdx.x == 0) {
        atomicAdd(ctr, 1u);
        while (atomicAdd(ctr, 0u) < target)
            __builtin_amdgcn_s_sleep(8);
    }
    __syncthreads();
    __threadfence();                 // acquire: no stale reads after barrier
}

// ---------------------------------------------------------------------------
// k0: pack BhatF, fragment-major f_p*B_tilde: BhatF[(h>>5)<<14 | p'<<5 | h&31]
// and ChatF[kk<<12 | h<<5 | col&31] = fragment-major [Cr,-Ci].
// ---------------------------------------------------------------------------
__global__ __launch_bounds__(256) void k0(
    const float* __restrict__ logLr, const float* __restrict__ Lim,
    const float* __restrict__ logDt,
    const float* __restrict__ Br, const float* __restrict__ Bi,
    const float* __restrict__ Cr, const float* __restrict__ Ci,
    unsigned short* __restrict__ BhatF, unsigned short* __restrict__ ChatF)
{
    const int tid = blockIdx.x * 256 + threadIdx.x;  // 32768 = P*H
    const int p = tid >> 7, h = tid & 127;
    float wr, wi; discretize(logLr, Lim, logDt, p, wr, wi);
    const float Lr = expf(logLr[p]), li = Lim[p];
    const float nr = wr - 1.0f, ni = wi;
    const float den = Lr * Lr + li * li;
    const float fr = (-nr * Lr + ni * li) / den;
    const float fi = (-ni * Lr - nr * li) / den;
    const float br = Br[p * NH + h], bi = Bi[p * NH + h];
    BhatF[((size_t)(h >> 5) << 14) + ((2 * p)     << 5) + (h & 31)] = f2bf(fr * br - fi * bi);
    BhatF[((size_t)(h >> 5) << 14) + ((2 * p + 1) << 5) + (h & 31)] = f2bf(fr * bi + fi * br);
    const int col0 = 2 * p, col1 = 2 * p + 1;
    ChatF[((size_t)(col0 >> 5) << 12) + (h << 5) + (col0 & 31)] = f2bf(Cr[h * NP + p]);
    ChatF[((size_t)(col1 >> 5) << 12) + (h << 5) + (col1 & 31)] = f2bf(-Ci[h * NP + p]);
}

// ---------------------------------------------------------------------------
// gAll: fusion of r8's gA + s2 + gF with software grid barriers replacing the
// two kernel boundaries. Grid 1024x256, 2 tiles/block (t = bid, bid+1024).
// All phase arithmetic is r8-verbatim -> absmax unchanged (0.0625).
// ---------------------------------------------------------------------------
__global__ __launch_bounds__(256, 4) void gAll(
    const float* __restrict__ u, const unsigned short* __restrict__ BhatF,
    const unsigned short* __restrict__ ChatF,
    const float* __restrict__ logLr, const float* __restrict__ Lim,
    const float* __restrict__ logDt, float2* __restrict__ part,
    const float* __restrict__ Dv, float* __restrict__ out,
    unsigned* __restrict__ bars)
{
    __shared__ __align__(16) char smem[25216];
    unsigned short (*us)[136] = (unsigned short(*)[136])smem;   // 8704 B (A & C)
    unsigned* xs = (unsigned*)(smem + 8704);                    // 16512 B (phase A)
    char* osb = smem + 8704;                                    // 16384 B (phase C)

    const int tid = threadIdx.x;
    const int w = tid >> 6, lane = tid & 63;
    const int q = lane >> 4, c = lane & 15;

    // ======================= PHASE A: GEMM1 + carries =======================
    for (int it = 0; it < 2; ++it) {
        const int t = (int)blockIdx.x + it * 1024;
        const int b = t >> 6, m = t & 63;
        const int l0 = m * 32;

        __syncthreads();   // prev tile's xs scan reads done
        {   // stage u tile (32 l x 128 h) fp32 -> bf16 LDS — once per tile
            const int lrow = tid >> 3;
            const int hcol = (tid & 7) * 16;
            const float* up = u + (size_t)(l0 + lrow) * (NB * NH) + b * NH + hcol;
            float4 a = *(const float4*)(up + 0);
            float4 d = *(const float4*)(up + 4);
            float4 e = *(const float4*)(up + 8);
            float4 g = *(const float4*)(up + 12);
            uint4 w0, w1;
            w0.x = (unsigned)f2bf(a.x) | ((unsigned)f2bf(a.y) << 16);
            w0.y = (unsigned)f2bf(a.z) | ((unsigned)f2bf(a.w) << 16);
            w0.z = (unsigned)f2bf(d.x) | ((unsigned)f2bf(d.y) << 16);
            w0.w = (unsigned)f2bf(d.z) | ((unsigned)f2bf(d.w) << 16);
            w1.x = (unsigned)f2bf(e.x) | ((unsigned)f2bf(e.y) << 16);
            w1.y = (unsigned)f2bf(e.z) | ((unsigned)f2bf(e.w) << 16);
            w1.z = (unsigned)f2bf(g.x) | ((unsigned)f2bf(g.y) << 16);
            w1.w = (unsigned)f2bf(g.z) | ((unsigned)f2bf(g.w) << 16);
            *(uint4*)&us[lrow][hcol + 0] = w0;
            *(uint4*)&us[lrow][hcol + 8] = w1;
        }
        __syncthreads();   // us ready

        #pragma unroll 1
        for (int ph = 0; ph < 2; ++ph) {
            const int pbase = ph * 256 + w * 64;

            f32x4 acc[4][2];
            #pragma unroll
            for (int mt = 0; mt < 4; ++mt)
                #pragma unroll
                for (int nt = 0; nt < 2; ++nt) acc[mt][nt] = (f32x4){0.f, 0.f, 0.f, 0.f};

            #pragma unroll
            for (int kk = 0; kk < 4; ++kk) {
                bf16x8 af[4];
                #pragma unroll
                for (int mt = 0; mt < 4; ++mt)
                    af[mt] = *(const bf16x8*)(BhatF + ((size_t)kk << 14)
                                              + ((pbase + 16 * mt + c) << 5) + 8 * q);
                bf16x8 bfr[2];
                #pragma unroll
                for (int nt = 0; nt < 2; ++nt)
                    bfr[nt] = *(const bf16x8*)&us[16 * nt + c][kk * 32 + 8 * q];
                #pragma unroll
                for (int mt = 0; mt < 4; ++mt)
                    #pragma unroll
                    for (int nt = 0; nt < 2; ++nt)
                        acc[mt][nt] = __builtin_amdgcn_mfma_f32_16x16x32_bf16(
                            af[mt], bfr[nt], acc[mt][nt], 0, 0, 0);
            }

            // stash xs (bf16 pack — identical rounding everywhere)
            #pragma unroll
            for (int mt = 0; mt < 4; ++mt)
                #pragma unroll
                for (int nt = 0; nt < 2; ++nt) {
                    const int rw  = 16 * nt + c;
                    const int ppl = w * 64 + 16 * mt + 4 * q;
                    ushort4 st;
                    st.x = f2bf(acc[mt][nt][0]); st.y = f2bf(acc[mt][nt][1]);
                    st.z = f2bf(acc[mt][nt][2]); st.w = f2bf(acc[mt][nt][3]);
                    const int col = (ppl >> 1);
                    xs[rw * 129 + col]     = (unsigned)st.x | ((unsigned)st.y << 16);
                    xs[rw * 129 + col + 1] = (unsigned)st.z | ((unsigned)st.w << 16);
                }
            __syncthreads();   // xs ready

            // carry-only scan over 32 rows (threads 0..127 own this half's p)
            if (tid < 128) {
                float wr, wi; discretize(logLr, Lim, logDt, ph * 128 + tid, wr, wi);
                float sr = 0.f, si = 0.f;
                unsigned va[8], vb[8];
                #pragma unroll
                for (int j = 0; j < 8; ++j) va[j] = xs[j * 129 + tid];
                #pragma unroll
                for (int k8 = 0; k8 < 4; ++k8) {
                    if (k8 < 3) {
                        #pragma unroll
                        for (int j = 0; j < 8; ++j) vb[j] = xs[((k8 + 1) * 8 + j) * 129 + tid];
                    }
                    #pragma unroll
                    for (int j = 0; j < 8; ++j) {
                        const float xr = bf2f((unsigned short)(va[j] & 0xffffu));
                        const float xi = bf2f((unsigned short)(va[j] >> 16));
                        const float tr = wr * sr - wi * si + xr;
                        const float ti = wr * si + wi * sr + xi;
                        sr = tr; si = ti;
                    }
                    #pragma unroll
                    for (int j = 0; j < 8; ++j) va[j] = vb[j];
                }
                part[((size_t)b * 64 + m) * NP + ph * 128 + tid] = make_float2(sr, si);
            }
            __syncthreads();   // scan reads done before next stash/stage
        }
    }
    gbar(bars + 0, 1024u);

    // ======================= PHASE B: s2 entry scan =========================
    if (blockIdx.x < NB) {
        const int b = blockIdx.x, p = tid;
        float wr, wi; discretize(logLr, Lim, logDt, p, wr, wi);
        float Wr = wr, Wi = wi;
        #pragma unroll
        for (int t = 0; t < 5; ++t) { const float r = Wr * Wr - Wi * Wi;
                                      Wi = 2.f * Wr * Wi; Wr = r; }   // w^32
        const size_t base = (size_t)b * 64 * NP + p;
        float sr = 0.f, si = 0.f;
        float2 va[8], vb[8];
        #pragma unroll
        for (int j = 0; j < 8; ++j) va[j] = part[base + (size_t)j * NP];
        #pragma unroll
        for (int k8 = 0; k8 < 8; ++k8) {
            if (k8 < 7) {
                #pragma unroll
                for (int j = 0; j < 8; ++j)
                    vb[j] = part[base + (size_t)((k8 + 1) * 8 + j) * NP];
            }
            #pragma unroll
            for (int j = 0; j < 8; ++j) {
                part[base + (size_t)(k8 * 8 + j) * NP] = make_float2(sr, si);  // entry
                const float tr = Wr * sr - Wi * si + va[j].x;
                const float ti = Wr * si + Wi * sr + va[j].y;
                sr = tr; si = ti;
            }
            #pragma unroll
            for (int j = 0; j < 8; ++j) va[j] = vb[j];
        }
    }
    gbar(bars + 16, 1024u);

    // ======== PHASE C: GEMM1 recompute + replay + GEMM2 (r8-gF body) ========
    for (int it = 0; it < 2; ++it) {
        const int t = (int)blockIdx.x + it * 1024;
        const int b = t >> 6, m = t & 63;
        const int l0 = m * 32;
        const int hbase = w * 32;

        __syncthreads();   // prev tile's osb GEMM2 reads done
        {   // stage u tile
            const int lrow = tid >> 3;
            const int hcol = (tid & 7) * 16;
            const float* up = u + (size_t)(l0 + lrow) * (NB * NH) + b * NH + hcol;
            float4 a = *(const float4*)(up + 0);
            float4 d = *(const float4*)(up + 4);
            float4 e = *(const float4*)(up + 8);
            float4 g = *(const float4*)(up + 12);
            uint4 w0, w1;
            w0.x = (unsigned)f2bf(a.x) | ((unsigned)f2bf(a.y) << 16);
            w0.y = (unsigned)f2bf(a.z) | ((unsigned)f2bf(a.w) << 16);
            w0.z = (unsigned)f2bf(d.x) | ((unsigned)f2bf(d.y) << 16);
            w0.w = (unsigned)f2bf(d.z) | ((unsigned)f2bf(d.w) << 16);
            w1.x = (unsigned)f2bf(e.x) | ((unsigned)f2bf(e.y) << 16);
            w1.y = (unsigned)f2bf(e.z) | ((unsigned)f2bf(e.w) << 16);
            w1.z = (unsigned)f2bf(g.x) | ((unsigned)f2bf(g.y) << 16);
            w1.w = (unsigned)f2bf(g.z) | ((unsigned)f2bf(g.w) << 16);
            *(uint4*)&us[lrow][hcol + 0] = w0;
            *(uint4*)&us[lrow][hcol + 8] = w1;
        }
        __syncthreads();   // us ready

        f32x4 acc2[2][2];
        #pragma unroll
        for (int mt = 0; mt < 2; ++mt)
            #pragma unroll
            for (int nt = 0; nt < 2; ++nt) acc2[mt][nt] = (f32x4){0.f, 0.f, 0.f, 0.f};

        #pragma unroll 1
        for (int half = 0; half < 2; ++half) {
            const int pbase = half * 256 + w * 64;
            f32x4 acc[4][2];
            #pragma unroll
            for (int mt = 0; mt < 4; ++mt)
                #pragma unroll
                for (int nt = 0; nt < 2; ++nt) acc[mt][nt] = (f32x4){0.f, 0.f, 0.f, 0.f};
            #pragma unroll
            for (int kk = 0; kk < 4; ++kk) {
                bf16x8 af[4];
                #pragma unroll
                for (int mt = 0; mt < 4; ++mt)
                    af[mt] = *(const bf16x8*)(BhatF + ((size_t)kk << 14)
                                              + ((pbase + 16 * mt + c) << 5) + 8 * q);
                bf16x8 bfr[2];
                #pragma unroll
                for (int nt = 0; nt < 2; ++nt)
                    bfr[nt] = *(const bf16x8*)&us[16 * nt + c][kk * 32 + 8 * q];
                #pragma unroll
                for (int mt = 0; mt < 4; ++mt)
                    #pragma unroll
                    for (int nt = 0; nt < 2; ++nt)
                        acc[mt][nt] = __builtin_amdgcn_mfma_f32_16x16x32_bf16(
                            af[mt], bfr[nt], acc[mt][nt], 0, 0, 0);
            }

            // stash bf16 Bu into swizzled osb
            #pragma unroll
            for (int mt = 0; mt < 4; ++mt)
                #pragma unroll
                for (int nt = 0; nt < 2; ++nt) {
                    const int row  = 16 * nt + c;
                    const int col2 = w * 32 + 8 * mt + 2 * q;
                    ushort4 st;
                    st.x = f2bf(acc[mt][nt][0]); st.y = f2bf(acc[mt][nt][1]);
                    st.z = f2bf(acc[mt][nt][2]); st.w = f2bf(acc[mt][nt][3]);
                    const unsigned byte = (((unsigned)row << 9)
                                           + (((unsigned)col2 << 2)
                                              ^ (((unsigned)(row & 7)) << 4)));
                    uint2 st2 = { (unsigned)st.x | ((unsigned)st.y << 16),
                                  (unsigned)st.z | ((unsigned)st.w << 16) };
                    *(uint2*)(osb + byte) = st2;
                }
            __syncthreads();   // osb Bu ready

            // replay in place from entry (threads 0..127, batch-loaded)
            if (tid < 128) {
                const int p = half * 128 + tid;
                float wr, wi; discretize(logLr, Lim, logDt, p, wr, wi);
                const float2 E = part[((size_t)(b * 64 + m)) * NP + p];
                float sr = E.x, si = E.y;
                unsigned va[32];
                #pragma unroll
                for (int j = 0; j < 32; ++j) {
                    const unsigned byte = (((unsigned)j << 9)
                                           + (((unsigned)tid << 2)
                                              ^ (((unsigned)(j & 7)) << 4)));
                    va[j] = *(const unsigned*)(osb + byte);
                }
                #pragma unroll
                for (int j = 0; j < 32; ++j) {
                    const float xr = bf2f((unsigned short)(va[j] & 0xffffu));
                    const float xi = bf2f((unsigned short)(va[j] >> 16));
                    const float tr = wr * sr - wi * si + xr;
                    const float ti = wr * si + wi * sr + xi;
                    sr = tr; si = ti;
                    va[j] = (unsigned)f2bf(tr) | ((unsigned)f2bf(ti) << 16);
                }
                #pragma unroll
                for (int j = 0; j < 32; ++j) {
                    const unsigned byte = (((unsigned)j << 9)
                                           + (((unsigned)tid << 2)
                                              ^ (((unsigned)(j & 7)) << 4)));
                    *(unsigned*)(osb + byte) = va[j];
                }
            }
            __syncthreads();   // replayed o ready

            // GEMM2 this half's 8 kk (acc2 persists across halves)
            #pragma unroll 4
            for (int kl = 0; kl < 8; ++kl) {
                const int kk = half * 8 + kl;
                bf16x8 af2[2];
                #pragma unroll
                for (int mt = 0; mt < 2; ++mt)
                    af2[mt] = *(const bf16x8*)(ChatF + ((size_t)kk << 12)
                                               + ((hbase + (mt << 4) + c) << 5) + (q << 3));
                bf16x8 bfr2[2];
                #pragma unroll
                for (int nt = 0; nt < 2; ++nt) {
                    const int r = 16 * nt + c;
                    const unsigned byte = ((((unsigned)r << 9) + ((unsigned)kl << 6)
                                            + ((unsigned)q << 4))
                                           ^ (((unsigned)(c & 7)) << 4));
                    bfr2[nt] = *(const bf16x8*)(osb + byte);
                }
                #pragma unroll
                for (int mt = 0; mt < 2; ++mt)
                    #pragma unroll
                    for (int nt = 0; nt < 2; ++nt)
                        acc2[mt][nt] = __builtin_amdgcn_mfma_f32_16x16x32_bf16(
                            af2[mt], bfr2[nt], acc2[mt][nt], 0, 0, 0);
            }
            if (half == 0) __syncthreads();   // osb consumed before overwrite
        }

        // epilogue: D-term + out
        #pragma unroll
        for (int mt = 0; mt < 2; ++mt) {
            const int h4 = hbase + 16 * mt + 4 * q;
            const float4 dd = *(const float4*)(Dv + h4);
            #pragma unroll
            for (int nt = 0; nt < 2; ++nt) {
                const int l = l0 + 16 * nt + c;
                const size_t off = ((size_t)l * NB + b) * NH + h4;
                const float4 uu = *(const float4*)(u + off);
                float4 ov;
                ov.x = acc2[mt][nt][0] + dd.x * uu.x;
                ov.y = acc2[mt][nt][1] + dd.y * uu.y;
                ov.z = acc2[mt][nt][2] + dd.z * uu.z;
                ov.w = acc2[mt][nt][3] + dd.w * uu.w;
                *(float4*)(out + off) = ov;
            }
        }
    }
}

extern "C" void kernel_launch(void* const* d_in, const int* in_sizes, int n_in,
                              void* d_out, int out_size, void* d_ws, size_t ws_size,
                              hipStream_t stream)
{
    const float* u     = (const float*)d_in[0];
    const float* logLr = (const float*)d_in[1];
    const float* Lim   = (const float*)d_in[2];
    const float* Btr   = (const float*)d_in[3];
    const float* Bti   = (const float*)d_in[4];
    const float* Ctr   = (const float*)d_in[5];
    const float* Cti   = (const float*)d_in[6];
    const float* Dv    = (const float*)d_in[7];
    const float* logDt = (const float*)d_in[8];
    float* out = (float*)d_out;

    char* ws = (char*)d_ws;
    float2*         part = (float2*)ws;                          //  4,194,304 B (carries -> entries in place)
    unsigned short* Bhat = (unsigned short*)(ws + 4194304);      //    131,072 B (BhatF)
    unsigned short* Chat = (unsigned short*)(ws + 4325376);      //    131,072 B (ChatF)
    unsigned*       bars = (unsigned*)(ws + 4456448);            //        128 B (2 barrier ctrs)

    hipMemsetAsync(bars, 0, 128, stream);
    k0<<<dim3((NP * NH) / 256), 256, 0, stream>>>(logLr, Lim, logDt,
                                                  Btr, Bti, Ctr, Cti, Bhat, Chat);
    gAll<<<dim3(1024), 256, 0, stream>>>(u, Bhat, Chat, logLr, Lim, logDt,
                                         part, Dv, out, bars);
}